// Round 5
// baseline (9517.416 us; speedup 1.0000x reference)
//
#include <hip/hip_runtime.h>
#include <cstddef>
#include <cstdint>

// Problem constants (from reference)
#define SEQB   8
#define SEQL   2048
#define DMODEL 1024
#define DINNER 2048
#define DSTATE 16
#define NC     32            // scan chunks along t
#define TC     64            // SEQL/NC

typedef __attribute__((ext_vector_type(4))) float f32x4;
typedef __attribute__((ext_vector_type(8))) short bf16x8;
typedef unsigned int u32;
typedef const __attribute__((address_space(1))) u32* gas_ptr;
typedef __attribute__((address_space(3))) u32* las_ptr;

__device__ __forceinline__ void gld16(const void* g, void* l){
  __builtin_amdgcn_global_load_lds((gas_ptr)g, (las_ptr)l, 16, 0, 0);
}

__device__ __forceinline__ float siluf(float x){ return x / (1.f + __expf(-x)); }
__device__ __forceinline__ float softplusf(float x){ return (x > 20.f) ? x : log1pf(__expf(x)); }

// RNE fp32 -> bf16 bits
__device__ __forceinline__ unsigned short f2bf_rne(float f){
  unsigned int u = __float_as_uint(f);
  u += 0x7FFFu + ((u>>16)&1u);
  return (unsigned short)(u>>16);
}
__device__ __forceinline__ void split_bf(float f, unsigned short& h, unsigned short& l){
  unsigned short hs = f2bf_rne(f);
  float hf = __uint_as_float(((unsigned int)hs)<<16);
  h = hs;
  l = f2bf_rne(f - hf);
}

// Convert 8 consecutive fp32 at PSRC into hi/lo bf16x8 and store (generic ptr).
#define CV8(PH, PL, PSRC) { \
  const float4* _p4 = (const float4*)(PSRC); \
  float4 _a = _p4[0], _b = _p4[1]; \
  bf16x8 _H, _L; unsigned short _h,_l; \
  split_bf(_a.x,_h,_l); _H[0]=(short)_h; _L[0]=(short)_l; \
  split_bf(_a.y,_h,_l); _H[1]=(short)_h; _L[1]=(short)_l; \
  split_bf(_a.z,_h,_l); _H[2]=(short)_h; _L[2]=(short)_l; \
  split_bf(_a.w,_h,_l); _H[3]=(short)_h; _L[3]=(short)_l; \
  split_bf(_b.x,_h,_l); _H[4]=(short)_h; _L[4]=(short)_l; \
  split_bf(_b.y,_h,_l); _H[5]=(short)_h; _L[5]=(short)_l; \
  split_bf(_b.z,_h,_l); _H[6]=(short)_h; _L[6]=(short)_l; \
  split_bf(_b.w,_h,_l); _H[7]=(short)_h; _L[7]=(short)_l; \
  *(bf16x8*)(PH) = _H; *(bf16x8*)(PL) = _L; }

// ---------------------------------------------------------------------------
// Weight pre-split (B-operand mode {h, l, h}): src [R][K] fp32 -> dst [R][3K]
// bf16.  Flat thread per 4 elems; K power of 2, k4shift = log2(K/4).
// ---------------------------------------------------------------------------
__global__ __launch_bounds__(256)
void wsplit(const float* __restrict__ src, unsigned short* __restrict__ dst,
            int K, int k4shift)
{
  int idx = blockIdx.x*256 + threadIdx.x;
  int r  = idx >> k4shift;
  int c4 = idx & ((1<<k4shift)-1);
  float4 v = ((const float4*)src)[idx];
  unsigned short h,l; short4 h4, l4;
  split_bf(v.x,h,l); h4.x=(short)h; l4.x=(short)l;
  split_bf(v.y,h,l); h4.y=(short)h; l4.y=(short)l;
  split_bf(v.z,h,l); h4.z=(short)h; l4.z=(short)l;
  split_bf(v.w,h,l); h4.w=(short)h; l4.w=(short)l;
  size_t ro = (size_t)r*3*K;
  *(short4*)&dst[ro + (c4<<2)]        = h4;
  *(short4*)&dst[ro + K + (c4<<2)]    = l4;
  *(short4*)&dst[ro + 2*K + (c4<<2)]  = h4;
}

// ---------------------------------------------------------------------------
// LayerNorm (+ optional residual) fused with A-operand split {h, h, l}:
// writes Hs [row][3*1024] bf16 only (no fp32 output needed).
// ---------------------------------------------------------------------------
__global__ __launch_bounds__(256)
void ln_split(const float* __restrict__ a, const float* __restrict__ res,
              const float* __restrict__ w, const float* __restrict__ bias,
              unsigned short* __restrict__ Hs)
{
  int row = blockIdx.x;
  size_t off = (size_t)row * DMODEL;
  float4 v = ((const float4*)(a + off))[threadIdx.x];
  if (res){
    float4 u = ((const float4*)(res + off))[threadIdx.x];
    v.x += u.x; v.y += u.y; v.z += u.z; v.w += u.w;
  }
  float s  = v.x + v.y + v.z + v.w;
  float s2 = fmaf(v.x,v.x, fmaf(v.y,v.y, fmaf(v.z,v.z, v.w*v.w)));
  #pragma unroll
  for (int o=32;o>0;o>>=1){ s += __shfl_down(s,o,64); s2 += __shfl_down(s2,o,64); }
  __shared__ float red[8];
  int lane = threadIdx.x & 63, wid = threadIdx.x >> 6;
  if (lane==0){ red[wid]=s; red[4+wid]=s2; }
  __syncthreads();
  s  = red[0]+red[1]+red[2]+red[3];
  s2 = red[4]+red[5]+red[6]+red[7];
  float mu  = s * (1.f/DMODEL);
  float var = s2 * (1.f/DMODEL) - mu*mu;
  float rstd = rsqrtf(var + 1e-5f);
  float4 wv = ((const float4*)w)[threadIdx.x];
  float4 bv = ((const float4*)bias)[threadIdx.x];
  float4 o4;
  o4.x = (v.x-mu)*rstd*wv.x + bv.x;
  o4.y = (v.y-mu)*rstd*wv.y + bv.y;
  o4.z = (v.z-mu)*rstd*wv.z + bv.z;
  o4.w = (v.w-mu)*rstd*wv.w + bv.w;
  unsigned short h,l; short4 h4, l4;
  split_bf(o4.x,h,l); h4.x=(short)h; l4.x=(short)l;
  split_bf(o4.y,h,l); h4.y=(short)h; l4.y=(short)l;
  split_bf(o4.z,h,l); h4.z=(short)h; l4.z=(short)l;
  split_bf(o4.w,h,l); h4.w=(short)h; l4.w=(short)l;
  size_t ro = (size_t)row*3072;
  int c = threadIdx.x<<2;
  *(short4*)&Hs[ro + c]        = h4;
  *(short4*)&Hs[ro + 1024 + c] = h4;
  *(short4*)&Hs[ro + 2048 + c] = l4;
}

// ---------------------------------------------------------------------------
// bf16 NT GEMM (m97 structure): C[m,n] = sum_k' A[m,k']*B[n,k'], fp32 out.
// A [M][K3], B [N][K3] pre-split bf16 triples; K3 = 3K carries the split-fp32
// correction terms. 128x128 tile, BK=32, global_load_lds w=16 with
// both-sides XOR swizzle (slot ^= (row>>1)&3 -> 2-way bank aliasing = free).
// 4 waves, each 64x64 quadrant of 4x4 16x16x32 frags. M,N multiples of 128.
// ---------------------------------------------------------------------------
__global__ __launch_bounds__(256)
void mgemm_bf3(const unsigned short* __restrict__ A, int lda,
               const unsigned short* __restrict__ B, int ldb,
               float* __restrict__ C, int ldc, int K3)
{
  __shared__ __align__(16) unsigned short As[128*32];
  __shared__ __align__(16) unsigned short Bs[128*32];
  const int t = threadIdx.x;
  const int mbase = blockIdx.y << 7, nbase = blockIdx.x << 7;
  const int lane = t & 63, w = t >> 6;
  const int wr = w >> 1, wc = w & 1;
  const int l16 = lane & 15, kq = lane >> 4;

  // staging coords: idx = t (rows 0..63 x 4 slots), idx = t+256 (rows 64..127)
  const int srow = t >> 2, sl = t & 3;
  const int co0 = ((sl ^ ((srow>>1)&3)) << 3);
  const int co1 = ((sl ^ (((srow+64)>>1)&3)) << 3);
  const unsigned short* pa0 = A + (size_t)(mbase+srow)*lda + co0;
  const unsigned short* pa1 = A + (size_t)(mbase+srow+64)*lda + co1;
  const unsigned short* pb0 = B + (size_t)(nbase+srow)*ldb + co0;
  const unsigned short* pb1 = B + (size_t)(nbase+srow+64)*ldb + co1;
  unsigned short* da0 = &As[srow*32 + sl*8];
  unsigned short* da1 = &As[(srow+64)*32 + sl*8];
  unsigned short* db0 = &Bs[srow*32 + sl*8];
  unsigned short* db1 = &Bs[(srow+64)*32 + sl*8];

  f32x4 acc[4][4];
  #pragma unroll
  for (int i=0;i<4;i++)
    #pragma unroll
    for (int j=0;j<4;j++) acc[i][j] = (f32x4){0.f,0.f,0.f,0.f};

  for (int k0 = 0; k0 < K3; k0 += 32){
    gld16(pa0 + k0, da0);
    gld16(pa1 + k0, da1);
    gld16(pb0 + k0, db0);
    gld16(pb1 + k0, db1);
    __syncthreads();
    bf16x8 af[4];
    #pragma unroll
    for (int mf=0; mf<4; mf++){
      int ra = wr*64 + mf*16 + l16;
      af[mf] = *(const bf16x8*)&As[ra*32 + ((kq ^ ((ra>>1)&3))<<3)];
    }
    #pragma unroll
    for (int nf=0; nf<4; nf++){
      int rb = wc*64 + nf*16 + l16;
      bf16x8 bfr = *(const bf16x8*)&Bs[rb*32 + ((kq ^ ((rb>>1)&3))<<3)];
      #pragma unroll
      for (int mf=0; mf<4; mf++)
        acc[mf][nf] = __builtin_amdgcn_mfma_f32_16x16x32_bf16(af[mf], bfr, acc[mf][nf], 0,0,0);
    }
    __syncthreads();
  }

  #pragma unroll
  for (int mf=0; mf<4; mf++){
    int r0 = mbase + wr*64 + mf*16 + kq*4;
    #pragma unroll
    for (int nf=0; nf<4; nf++){
      int c = nbase + wc*64 + nf*16 + l16;
      #pragma unroll
      for (int r=0;r<4;r++)
        C[(size_t)(r0+r)*ldc + c] = acc[mf][nf][r];
    }
  }
}

// ---------------------------------------------------------------------------
// x_proj MFMA kernel (in-kernel split, small): XD[m,0..95] = sum_k XC[m,k]W[n,k]
// ---------------------------------------------------------------------------
__global__ __launch_bounds__(256)
void xproj_mfma(const float* __restrict__ A,  // [M][2048]
                const float* __restrict__ W,  // [96][2048]
                float* __restrict__ XD)       // [M][96]
{
  __shared__ __align__(16) unsigned short Ah[32][40], Al[32][40];
  __shared__ __align__(16) unsigned short Bh[96][40], Bl[96][40];
  const int t = threadIdx.x;
  const int mbase = blockIdx.x << 5;
  const int lane = t & 63, w = t >> 6;
  const int mf = w & 1, nc0 = (w >> 1) * 48;
  const int l16 = lane & 15, kq = lane >> 4;
  const bool isA = (t < 64);
  const int srow = (isA ? t : (t - 64)) >> 1;
  const int shalf = (t & 1) << 4;
  const float* ps = isA ? (A + (size_t)(mbase + srow)*2048 + shalf)
                        : (W + (size_t)srow*2048 + shalf);
  unsigned short* dH = isA ? &Ah[srow][shalf] : &Bh[srow][shalf];
  unsigned short* dL = isA ? &Al[srow][shalf] : &Bl[srow][shalf];

  f32x4 acc[3];
  #pragma unroll
  for (int j=0;j<3;j++) acc[j] = (f32x4){0.f,0.f,0.f,0.f};

  for (int k0=0; k0<2048; k0+=32){
    CV8(dH,   dL,   ps + k0);
    CV8(dH+8, dL+8, ps + k0 + 8);
    __syncthreads();
    bf16x8 ah = *(const bf16x8*)&Ah[mf*16 + l16][kq*8];
    bf16x8 av = *(const bf16x8*)&Al[mf*16 + l16][kq*8];
    #pragma unroll
    for (int nf=0; nf<3; nf++){
      int br = nc0 + nf*16 + l16;
      bf16x8 bh = *(const bf16x8*)&Bh[br][kq*8];
      bf16x8 bl = *(const bf16x8*)&Bl[br][kq*8];
      acc[nf] = __builtin_amdgcn_mfma_f32_16x16x32_bf16(ah, bh, acc[nf], 0,0,0);
      acc[nf] = __builtin_amdgcn_mfma_f32_16x16x32_bf16(ah, bl, acc[nf], 0,0,0);
      acc[nf] = __builtin_amdgcn_mfma_f32_16x16x32_bf16(av, bh, acc[nf], 0,0,0);
    }
    __syncthreads();
  }
  #pragma unroll
  for (int nf=0; nf<3; nf++){
    int c = nc0 + nf*16 + l16;
    int r0 = mbase + mf*16 + kq*4;
    #pragma unroll
    for (int r=0;r<4;r++)
      XD[(size_t)(r0+r)*96 + c] = acc[nf][r];
  }
}

// ---------------------------------------------------------------------------
// fp32 NT GEMM (dt_proj, K=64): C = softplus(A*B^T + ebias[n])
// ---------------------------------------------------------------------------
template<int EPI>
__global__ __launch_bounds__(256)
void gemm_nt(const float* __restrict__ A, int lda,
             const float* __restrict__ B, int ldb,
             float* __restrict__ C, int ldc,
             int N, int K,
             const float* __restrict__ ebias)
{
  __shared__ float As[16][132];
  __shared__ float Bs[16][132];
  int tid = threadIdx.x;
  int tx = tid & 15, ty = tid >> 4;
  int mbase = blockIdx.y << 7;
  int nbase = blockIdx.x << 7;
  float acc[8][8];
  #pragma unroll
  for (int i=0;i<8;i++)
    #pragma unroll
    for (int j=0;j<8;j++) acc[i][j]=0.f;

  for (int k0=0;k0<K;k0+=16){
    #pragma unroll
    for (int it=0; it<2; it++){
      int idx = tid + (it<<8);
      int row = idx >> 2;
      int kq  = (idx & 3) << 2;
      float4 va = *(const float4*)(A + (size_t)(mbase+row)*lda + k0 + kq);
      As[kq+0][row]=va.x; As[kq+1][row]=va.y; As[kq+2][row]=va.z; As[kq+3][row]=va.w;
      int n = nbase + row;
      float4 vb = make_float4(0.f,0.f,0.f,0.f);
      if (n < N) vb = *(const float4*)(B + (size_t)n*ldb + k0 + kq);
      Bs[kq+0][row]=vb.x; Bs[kq+1][row]=vb.y; Bs[kq+2][row]=vb.z; Bs[kq+3][row]=vb.w;
    }
    __syncthreads();
    #pragma unroll
    for (int k=0;k<16;k++){
      float a[8], bb[8];
      *(float4*)&a[0]  = *(const float4*)&As[k][ty<<2];
      *(float4*)&a[4]  = *(const float4*)&As[k][64+(ty<<2)];
      *(float4*)&bb[0] = *(const float4*)&Bs[k][tx<<2];
      *(float4*)&bb[4] = *(const float4*)&Bs[k][64+(tx<<2)];
      #pragma unroll
      for (int i=0;i<8;i++)
        #pragma unroll
        for (int j=0;j<8;j++)
          acc[i][j] = fmaf(a[i], bb[j], acc[i][j]);
    }
    __syncthreads();
  }

  int n0 = nbase + (tx<<2);
  int n1 = n0 + 64;
  float4 eb0=make_float4(0,0,0,0), eb1=make_float4(0,0,0,0);
  if (EPI==1){
    eb0 = *(const float4*)(ebias + n0);
    eb1 = *(const float4*)(ebias + n1);
  }
  #pragma unroll
  for (int i=0;i<8;i++){
    int mrow = mbase + ((i<4) ? ((ty<<2)+i) : (64 + (ty<<2) + (i-4)));
    float4 c0 = make_float4(acc[i][0],acc[i][1],acc[i][2],acc[i][3]);
    float4 c1 = make_float4(acc[i][4],acc[i][5],acc[i][6],acc[i][7]);
    if (EPI==1){
      c0.x = softplusf(c0.x+eb0.x); c0.y = softplusf(c0.y+eb0.y);
      c0.z = softplusf(c0.z+eb0.z); c0.w = softplusf(c0.w+eb0.w);
      c1.x = softplusf(c1.x+eb1.x); c1.y = softplusf(c1.y+eb1.y);
      c1.z = softplusf(c1.z+eb1.z); c1.w = softplusf(c1.w+eb1.w);
    }
    *(float4*)(C + (size_t)mrow*ldc + n0) = c0;
    *(float4*)(C + (size_t)mrow*ldc + n1) = c1;
  }
}

// ---------------------------------------------------------------------------
// Causal depthwise conv (k=4) + bias + SiLU. Reads xi from XZ (stride 4096,
// cols 0..2047), writes u -> XC (stride 2048).
// ---------------------------------------------------------------------------
__global__ __launch_bounds__(256)
void conv_silu_kernel(const float* __restrict__ xz, const float* __restrict__ cw,
                      const float* __restrict__ cb, float* __restrict__ xc)
{
  int idx = blockIdx.x*256 + threadIdx.x;
  int d = idx & (DINNER-1);
  int g = idx >> 11;
  int t0 = (g & 511) << 2;
  int b = g >> 9;
  float4 w4 = *(const float4*)(cw + d*4);
  float bias = cb[d];
  const float* base = xz + (size_t)b*SEQL*4096 + d;
  float v[7];
  #pragma unroll
  for (int j=0;j<7;j++){
    int t = t0-3+j;
    v[j] = (t>=0) ? base[(size_t)t*4096] : 0.f;
  }
  float* outp = xc + ((size_t)b*SEQL + t0)*DINNER + d;
  #pragma unroll
  for (int j=0;j<4;j++){
    float y = fmaf(v[j+3], w4.w, fmaf(v[j+2], w4.z, fmaf(v[j+1], w4.y, fmaf(v[j], w4.x, bias))));
    outp[(size_t)j*DINNER] = siluf(y);
  }
}

// ---------------------------------------------------------------------------
// Chunked selective scan.
// PASS 1: local scan from h=0; store h_final[16] -> hfin, sum(dt) -> sumdt.
// PASS 3: local scan from hfin (true chunk-initial state); y = C.h + u*D;
//         gate with z (from XZ col 2048+d); write gated y as split triple
//         {h,h,l} into GY [row][3*2048] bf16 (A-operand of out_proj).
// Thread = one (b, chunk, d). grid = NB*NC*8 blocks x 256.
// ---------------------------------------------------------------------------
template<int PASS>
__global__ __launch_bounds__(256)
void scan_chunk(const float* __restrict__ u_, const float* __restrict__ dt_,
                const float* __restrict__ xdbl,
                const float* __restrict__ xz, unsigned short* __restrict__ gy,
                const float* __restrict__ A_log, const float* __restrict__ Dp,
                float* __restrict__ hfin, float* __restrict__ sumdt)
{
  int idx = blockIdx.x*256 + threadIdx.x;
  int d = idx & (DINNER-1);
  int g = idx >> 11;
  int c = g & (NC-1);
  int b = g >> 5;

  float A2[16];
  {
    const float* al = A_log + (size_t)d*DSTATE;
    #pragma unroll
    for (int s=0;s<16;s++) A2[s] = -expf(al[s]) * 1.44269504f;
  }
  float h[16];
  if (PASS == 1){
    #pragma unroll
    for (int s=0;s<16;s++) h[s] = 0.f;
  } else {
    const float* hp = hfin + ((size_t)g*DINNER + d)*16;
    #pragma unroll
    for (int s=0;s<16;s+=4) *(float4*)&h[s] = *(const float4*)(hp + s);
  }
  float Dv = (PASS==3) ? Dp[d] : 0.f;

  size_t row0 = (size_t)b*SEQL + (size_t)c*TC;
  const float* pu  = u_  + row0*DINNER + d;
  const float* pdt = dt_ + row0*DINNER + d;
  const float* pz  = xz  + row0*4096 + 2048 + d;
  const float* pbc = xdbl + row0*96 + 64;

  float Bb[2][16], Cb[2][16];
#define LOAD_BC(buf, t) { const float4* p4 = (const float4*)(pbc + (size_t)(t)*96); \
    *(float4*)&Bb[buf][0]=p4[0]; *(float4*)&Bb[buf][4]=p4[1]; \
    *(float4*)&Bb[buf][8]=p4[2]; *(float4*)&Bb[buf][12]=p4[3]; \
    if (PASS==3){ \
    *(float4*)&Cb[buf][0]=p4[4]; *(float4*)&Cb[buf][4]=p4[5]; \
    *(float4*)&Cb[buf][8]=p4[6]; *(float4*)&Cb[buf][12]=p4[7]; } }

  LOAD_BC(0, 0);
  float sdt = 0.f;
  float dt_n = pdt[0];
  float u_n  = pu[0];
  float z_n  = (PASS==3) ? pz[0] : 0.f;

  for (int t=0; t<TC; t++){
    const int cur = t & 1, nxt = cur^1;
    float dtc = dt_n, uc = u_n, zc = z_n;
    if (t+1 < TC){
      dt_n = pdt[(size_t)(t+1)*DINNER];
      u_n  = pu [(size_t)(t+1)*DINNER];
      if (PASS==3) z_n = pz[(size_t)(t+1)*4096];
      LOAD_BC(nxt, t+1);
    }
    if (PASS==1) sdt += dtc;
    float du = dtc*uc;
    float y = 0.f;
    #pragma unroll
    for (int s=0;s<16;s++){
      float dA = exp2f(dtc*A2[s]);
      h[s] = fmaf(dA, h[s], du*Bb[cur][s]);
      if (PASS==3) y = fmaf(h[s], Cb[cur][s], y);
    }
    if (PASS==3){
      y = fmaf(uc, Dv, y);
      float gv = y * siluf(zc);
      unsigned short gh, gl;
      split_bf(gv, gh, gl);
      size_t ro = (row0 + t) * 6144;
      gy[ro + d]        = gh;
      gy[ro + 2048 + d] = gh;
      gy[ro + 4096 + d] = gl;
    }
  }
#undef LOAD_BC

  if (PASS==1){
    float* hp = hfin + ((size_t)g*DINNER + d)*16;
    #pragma unroll
    for (int s=0;s<16;s+=4) *(float4*)(hp + s) = *(const float4*)&h[s];
    sumdt[(size_t)g*DINNER + d] = sdt;
  }
}

// ---------------------------------------------------------------------------
// Propagate chunk-initial states: in-place hfin[c] := H_init(c).
// ---------------------------------------------------------------------------
__global__ __launch_bounds__(256)
void scan_prop(const float* __restrict__ A_log, float* __restrict__ hfin,
               const float* __restrict__ sumdt)
{
  int idx = blockIdx.x*256 + threadIdx.x;
  int s = idx & 15;
  int d = (idx >> 4) & (DINNER-1);
  int b = idx >> 15;
  float A2 = -expf(A_log[(size_t)d*DSTATE + s]) * 1.44269504f;
  float H = 0.f;
  size_t hbase = ((size_t)b*NC*DINNER + d)*16 + s;
  size_t sbase = (size_t)b*NC*DINNER + d;
  for (int c=0;c<NC;c++){
    float P   = exp2f(A2 * sumdt[sbase + (size_t)c*DINNER]);
    float tmp = hfin[hbase + (size_t)c*DINNER*16];
    hfin[hbase + (size_t)c*DINNER*16] = H;
    H = fmaf(P, H, tmp);
  }
}

// ---------------------------------------------------------------------------
// Launcher. Fixed: pre-split weights (75.5 MB). Per batch: XZ 32MB + XI 16 +
// XC 16 + SH 24MB (Hs then GY; disjoint lifetimes) + HF 4.25 + XD 0.75.
// X1 (layer-0 output) lives in d_out rows (row-local lifetime).
// ---------------------------------------------------------------------------
extern "C" void kernel_launch(void* const* d_in, const int* in_sizes, int n_in,
                              void* d_out, int out_size, void* d_ws, size_t ws_size,
                              hipStream_t stream)
{
  const float* x    = (const float*)d_in[0];
  const float* in_w = (const float*)d_in[1];
  const float* cw   = (const float*)d_in[2];
  const float* cb   = (const float*)d_in[3];
  const float* xpw  = (const float*)d_in[4];
  const float* dtw  = (const float*)d_in[5];
  const float* dtb  = (const float*)d_in[6];
  const float* A_log= (const float*)d_in[7];
  const float* Dp   = (const float*)d_in[8];
  const float* ow   = (const float*)d_in[9];
  const float* nw   = (const float*)d_in[10];
  const float* nb   = (const float*)d_in[11];
  float* outF = (float*)d_out;

  const size_t fixedB = 75497472ULL;     // INW3 50.33MB + OUTW3 25.17MB
  const size_t perB   = 97517568ULL;     // per-batch dynamic scratch
  int NB = 8;
  while (NB > 1 && fixedB + (size_t)NB*perB > ws_size) NB >>= 1;
  const int Mc = NB * SEQL;
  const int nchunk = SEQB / NB;

  unsigned short* INW3  = (unsigned short*)d_ws;           // [2][4096][3072]
  unsigned short* OUTW3 = INW3 + (size_t)8192*3072;        // [2][1024][6144]
  float* dyn = (float*)d_ws + fixedB/4;
  float* XZ = dyn;                                         // Mc*4096 (xi|z)
  float* XI = XZ + (size_t)Mc*4096;                        // Mc*2048 (dt)
  float* XC = XI + (size_t)Mc*2048;                        // Mc*2048 (u)
  unsigned short* SH = (unsigned short*)(XC + (size_t)Mc*2048); // Mc*6144 bf16
  float* HF = (float*)(SH + (size_t)Mc*6144);              // Mc*512
  float* SD = HF + (size_t)Mc*512;                         // Mc*32
  float* XD = SD + (size_t)Mc*32;                          // Mc*96

  // Pre-split weights: in_w (R=8192,K=1024) and out_w (R=2048,K=2048), {h,l,h}
  wsplit<<<8192, 256, 0, stream>>>(in_w, INW3, 1024, 8);
  wsplit<<<4096, 256, 0, stream>>>(ow,   OUTW3, 2048, 9);

  for (int c = 0; c < nchunk; ++c){
    const size_t rowoff = (size_t)c * Mc;
    const float* xrows = x + rowoff * DMODEL;
    float* X1 = outF + rowoff * DMODEL;     // layer-0 out / final out rows

    for (int l = 0; l < 2; ++l){
      const float* Al = A_log + (size_t)l*DINNER*DSTATE;

      // 1. LayerNorm (+ residual for layer 1) -> Hs (split triple)
      ln_split<<<Mc, 256, 0, stream>>>(
          (l==0) ? xrows : X1, (l==0) ? nullptr : xrows,
          nw + (size_t)l*DMODEL, nb + (size_t)l*DMODEL, SH);

      // 2. in_proj fused xi|z: (Mc x 3072) x (4096 x 3072)^T -> XZ
      mgemm_bf3<<<dim3(32, Mc/128), 256, 0, stream>>>(
          SH, 3072, INW3 + (size_t)l*4096*3072, 3072, XZ, 4096, 3072);

      // 3. causal conv + bias + SiLU: XZ[:, :2048] -> XC (u)
      conv_silu_kernel<<<NB*4096, 256, 0, stream>>>(
          XZ, cw + (size_t)l*DINNER*4, cb + (size_t)l*DINNER, XC);

      // 4. x_proj -> XD
      xproj_mfma<<<Mc/32, 256, 0, stream>>>(
          XC, xpw + (size_t)l*96*DINNER, XD);

      // 5. dt_proj + bias + softplus -> XI (dt)
      gemm_nt<1><<<dim3(16, Mc/128), 256, 0, stream>>>(
          XD, 96, dtw + (size_t)l*DINNER*64, 64, XI, DINNER, DINNER, 64,
          dtb + (size_t)l*DINNER);

      // 6. chunked scan; pass 3 gates with z and writes GY (split) into SH
      scan_chunk<1><<<NB*NC*8, 256, 0, stream>>>(
          XC, XI, XD, nullptr, nullptr, Al, Dp + (size_t)l*DINNER, HF, SD);
      scan_prop<<<NB*128, 256, 0, stream>>>(Al, HF, SD);
      scan_chunk<3><<<NB*NC*8, 256, 0, stream>>>(
          XC, XI, XD, XZ, SH, Al, Dp + (size_t)l*DINNER, HF, SD);

      // 7. out_proj: (Mc x 6144) x (1024 x 6144)^T -> X1 rows (both layers)
      mgemm_bf3<<<dim3(8, Mc/128), 256, 0, stream>>>(
          SH, 6144, OUTW3 + (size_t)l*1024*6144, 6144, X1, DMODEL, 6144);
    }
  }
}

// Round 6
// 6642.138 us; speedup vs baseline: 1.4329x; 1.4329x over previous
//
#include <hip/hip_runtime.h>
#include <cstddef>
#include <cstdint>

// Problem constants (from reference)
#define SEQB   8
#define SEQL   2048
#define DMODEL 1024
#define DINNER 2048
#define DSTATE 16
#define NC     32            // scan chunks along t
#define TC     64            // SEQL/NC

typedef __attribute__((ext_vector_type(4))) float f32x4;
typedef __attribute__((ext_vector_type(8))) short bf16x8;
typedef unsigned int u32;
typedef const __attribute__((address_space(1))) u32* gas_ptr;
typedef __attribute__((address_space(3))) u32* las_ptr;

__device__ __forceinline__ void gld16(const void* g, void* l){
  __builtin_amdgcn_global_load_lds((gas_ptr)g, (las_ptr)l, 16, 0, 0);
}

__device__ __forceinline__ float siluf(float x){ return x / (1.f + __expf(-x)); }
__device__ __forceinline__ float softplusf(float x){ return (x > 20.f) ? x : log1pf(__expf(x)); }

// RNE fp32 -> bf16 bits
__device__ __forceinline__ unsigned short f2bf_rne(float f){
  unsigned int u = __float_as_uint(f);
  u += 0x7FFFu + ((u>>16)&1u);
  return (unsigned short)(u>>16);
}
__device__ __forceinline__ void split_bf(float f, unsigned short& h, unsigned short& l){
  unsigned short hs = f2bf_rne(f);
  float hf = __uint_as_float(((unsigned int)hs)<<16);
  h = hs;
  l = f2bf_rne(f - hf);
}

// Convert 8 consecutive fp32 at PSRC into hi/lo bf16x8 and store (generic ptr).
#define CV8(PH, PL, PSRC) { \
  const float4* _p4 = (const float4*)(PSRC); \
  float4 _a = _p4[0], _b = _p4[1]; \
  bf16x8 _H, _L; unsigned short _h,_l; \
  split_bf(_a.x,_h,_l); _H[0]=(short)_h; _L[0]=(short)_l; \
  split_bf(_a.y,_h,_l); _H[1]=(short)_h; _L[1]=(short)_l; \
  split_bf(_a.z,_h,_l); _H[2]=(short)_h; _L[2]=(short)_l; \
  split_bf(_a.w,_h,_l); _H[3]=(short)_h; _L[3]=(short)_l; \
  split_bf(_b.x,_h,_l); _H[4]=(short)_h; _L[4]=(short)_l; \
  split_bf(_b.y,_h,_l); _H[5]=(short)_h; _L[5]=(short)_l; \
  split_bf(_b.z,_h,_l); _H[6]=(short)_h; _L[6]=(short)_l; \
  split_bf(_b.w,_h,_l); _H[7]=(short)_h; _L[7]=(short)_l; \
  *(bf16x8*)(PH) = _H; *(bf16x8*)(PL) = _L; }

// ---------------------------------------------------------------------------
// Weight pre-split PAIR {h|l}: src [R][K] fp32 -> dst [R][2K] bf16.
// ---------------------------------------------------------------------------
__global__ __launch_bounds__(256)
void wsplit2(const float* __restrict__ src, unsigned short* __restrict__ dst,
             int K, int k4shift)
{
  int idx = blockIdx.x*256 + threadIdx.x;
  int r  = idx >> k4shift;
  int c4 = idx & ((1<<k4shift)-1);
  float4 v = ((const float4*)src)[idx];
  unsigned short h,l; short4 h4, l4;
  split_bf(v.x,h,l); h4.x=(short)h; l4.x=(short)l;
  split_bf(v.y,h,l); h4.y=(short)h; l4.y=(short)l;
  split_bf(v.z,h,l); h4.z=(short)h; l4.z=(short)l;
  split_bf(v.w,h,l); h4.w=(short)h; l4.w=(short)l;
  size_t ro = (size_t)r*2*K;
  *(short4*)&dst[ro + (c4<<2)]     = h4;
  *(short4*)&dst[ro + K + (c4<<2)] = l4;
}

// ---------------------------------------------------------------------------
// LayerNorm (+ optional residual) fused with PAIR split {h|l}:
// writes Hs [row][2048] bf16 (cols 0..1023 = h, 1024..2047 = l).
// ---------------------------------------------------------------------------
__global__ __launch_bounds__(256)
void ln_split2(const float* __restrict__ a, const float* __restrict__ res,
               const float* __restrict__ w, const float* __restrict__ bias,
               unsigned short* __restrict__ Hs)
{
  int row = blockIdx.x;
  size_t off = (size_t)row * DMODEL;
  float4 v = ((const float4*)(a + off))[threadIdx.x];
  if (res){
    float4 u = ((const float4*)(res + off))[threadIdx.x];
    v.x += u.x; v.y += u.y; v.z += u.z; v.w += u.w;
  }
  float s  = v.x + v.y + v.z + v.w;
  float s2 = fmaf(v.x,v.x, fmaf(v.y,v.y, fmaf(v.z,v.z, v.w*v.w)));
  #pragma unroll
  for (int o=32;o>0;o>>=1){ s += __shfl_down(s,o,64); s2 += __shfl_down(s2,o,64); }
  __shared__ float red[8];
  int lane = threadIdx.x & 63, wid = threadIdx.x >> 6;
  if (lane==0){ red[wid]=s; red[4+wid]=s2; }
  __syncthreads();
  s  = red[0]+red[1]+red[2]+red[3];
  s2 = red[4]+red[5]+red[6]+red[7];
  float mu  = s * (1.f/DMODEL);
  float var = s2 * (1.f/DMODEL) - mu*mu;
  float rstd = rsqrtf(var + 1e-5f);
  float4 wv = ((const float4*)w)[threadIdx.x];
  float4 bv = ((const float4*)bias)[threadIdx.x];
  float4 o4;
  o4.x = (v.x-mu)*rstd*wv.x + bv.x;
  o4.y = (v.y-mu)*rstd*wv.y + bv.y;
  o4.z = (v.z-mu)*rstd*wv.z + bv.z;
  o4.w = (v.w-mu)*rstd*wv.w + bv.w;
  unsigned short h,l; short4 h4, l4;
  split_bf(o4.x,h,l); h4.x=(short)h; l4.x=(short)l;
  split_bf(o4.y,h,l); h4.y=(short)h; l4.y=(short)l;
  split_bf(o4.z,h,l); h4.z=(short)h; l4.z=(short)l;
  split_bf(o4.w,h,l); h4.w=(short)h; l4.w=(short)l;
  size_t ro = (size_t)row*2048;
  int c = threadIdx.x<<2;
  *(short4*)&Hs[ro + c]        = h4;
  *(short4*)&Hs[ro + 1024 + c] = l4;
}

// ---------------------------------------------------------------------------
// in_proj GEMM, pair-remap split-fp32: C = A*B^T with A,B stored as {h|l}
// pairs (K=1024 each half). Virtual K-loop of 3x1024 realizes hh+hl+lh.
// 128x128 tile, BK=32, gld16 staging, both-sides XOR swizzle (0 conflicts).
// Epilogue splits cols: n<2048 -> XI (xi), else -> ZB (z). M,N mult of 128.
// ---------------------------------------------------------------------------
__global__ __launch_bounds__(256)
void mgemm_in(const unsigned short* __restrict__ A,   // [M][2048] {h|l}
              const unsigned short* __restrict__ B,   // [4096][2048] {h|l}
              float* __restrict__ XI, float* __restrict__ ZB)
{
  __shared__ __align__(16) unsigned short As[128*32];
  __shared__ __align__(16) unsigned short Bs[128*32];
  const int t = threadIdx.x;
  const int mbase = blockIdx.y << 7, nbase = blockIdx.x << 7;
  const int lane = t & 63, w = t >> 6;
  const int wr = w >> 1, wc = w & 1;
  const int l16 = lane & 15, kq = lane >> 4;

  const int srow = t >> 2, sl = t & 3;
  const int co0 = ((sl ^ ((srow>>1)&3)) << 3);
  const int co1 = ((sl ^ (((srow+64)>>1)&3)) << 3);
  const unsigned short* pa0 = A + (size_t)(mbase+srow)*2048 + co0;
  const unsigned short* pa1 = A + (size_t)(mbase+srow+64)*2048 + co1;
  const unsigned short* pb0 = B + (size_t)(nbase+srow)*2048 + co0;
  const unsigned short* pb1 = B + (size_t)(nbase+srow+64)*2048 + co1;
  unsigned short* da0 = &As[srow*32 + sl*8];
  unsigned short* da1 = &As[(srow+64)*32 + sl*8];
  unsigned short* db0 = &Bs[srow*32 + sl*8];
  unsigned short* db1 = &Bs[(srow+64)*32 + sl*8];

  f32x4 acc[4][4];
  #pragma unroll
  for (int i=0;i<4;i++)
    #pragma unroll
    for (int j=0;j<4;j++) acc[i][j] = (f32x4){0.f,0.f,0.f,0.f};

  #pragma unroll
  for (int kb=0; kb<3; kb++){
    const int ao = (kb==2) ? 1024 : 0;   // A: {h,h,l}
    const int bo = (kb==1) ? 1024 : 0;   // B: {h,l,h}
    for (int kk=0; kk<1024; kk+=32){
      gld16(pa0 + ao + kk, da0);
      gld16(pa1 + ao + kk, da1);
      gld16(pb0 + bo + kk, db0);
      gld16(pb1 + bo + kk, db1);
      __syncthreads();
      bf16x8 af[4];
      #pragma unroll
      for (int mf=0; mf<4; mf++){
        int ra = wr*64 + mf*16 + l16;
        af[mf] = *(const bf16x8*)&As[ra*32 + ((kq ^ ((ra>>1)&3))<<3)];
      }
      #pragma unroll
      for (int nf=0; nf<4; nf++){
        int rb = wc*64 + nf*16 + l16;
        bf16x8 bfr = *(const bf16x8*)&Bs[rb*32 + ((kq ^ ((rb>>1)&3))<<3)];
        #pragma unroll
        for (int mf=0; mf<4; mf++)
          acc[mf][nf] = __builtin_amdgcn_mfma_f32_16x16x32_bf16(af[mf], bfr, acc[mf][nf], 0,0,0);
      }
      __syncthreads();
    }
  }

  float* Cd = (nbase < 2048) ? XI : ZB;
  const int cb = (nbase < 2048) ? nbase : (nbase - 2048);
  #pragma unroll
  for (int mf=0; mf<4; mf++){
    int r0 = mbase + wr*64 + mf*16 + kq*4;
    #pragma unroll
    for (int nf=0; nf<4; nf++){
      int c = cb + wc*64 + nf*16 + l16;
      #pragma unroll
      for (int r=0;r<4;r++)
        Cd[(size_t)(r0+r)*2048 + c] = acc[mf][nf][r];
    }
  }
}

// ---------------------------------------------------------------------------
// out_proj GEMM (round-4 proven): fp32 in/out, in-kernel split, 3 MFMAs/frag.
// 128x128 tile, BK=32. M,N multiples of 128.
// ---------------------------------------------------------------------------
__global__ __launch_bounds__(256)
void mgemm_cv(const float* __restrict__ A, int lda,
              const float* __restrict__ B, int ldb,
              float* __restrict__ C, int ldc, int K)
{
  __shared__ __align__(16) unsigned short Ah[128][40], Al[128][40];
  __shared__ __align__(16) unsigned short Bh[128][40], Bl[128][40];
  const int t = threadIdx.x;
  const int mbase = blockIdx.y << 7, nbase = blockIdx.x << 7;
  const int srow = t >> 1, shalf = (t & 1) << 4;
  const float* pa = A + (size_t)(mbase + srow)*lda + shalf;
  const float* pb = B + (size_t)(nbase + srow)*ldb + shalf;

  const int lane = t & 63, w = t >> 6;
  const int wr = w >> 1, wc = w & 1;
  const int l16 = lane & 15, kq = lane >> 4;

  f32x4 acc[4][4];
  #pragma unroll
  for (int i=0;i<4;i++)
    #pragma unroll
    for (int j=0;j<4;j++) acc[i][j] = (f32x4){0.f,0.f,0.f,0.f};

  for (int k0 = 0; k0 < K; k0 += 32){
    CV8(&Ah[srow][shalf],   &Al[srow][shalf],   pa + k0);
    CV8(&Ah[srow][shalf+8], &Al[srow][shalf+8], pa + k0 + 8);
    CV8(&Bh[srow][shalf],   &Bl[srow][shalf],   pb + k0);
    CV8(&Bh[srow][shalf+8], &Bl[srow][shalf+8], pb + k0 + 8);
    __syncthreads();
    bf16x8 ah[4], al[4];
    #pragma unroll
    for (int mf=0; mf<4; mf++){
      int ar = wr*64 + mf*16 + l16;
      ah[mf] = *(const bf16x8*)&Ah[ar][kq*8];
      al[mf] = *(const bf16x8*)&Al[ar][kq*8];
    }
    #pragma unroll
    for (int nf=0; nf<4; nf++){
      int br = wc*64 + nf*16 + l16;
      bf16x8 bh = *(const bf16x8*)&Bh[br][kq*8];
      bf16x8 bl = *(const bf16x8*)&Bl[br][kq*8];
      #pragma unroll
      for (int mf=0; mf<4; mf++){
        acc[mf][nf] = __builtin_amdgcn_mfma_f32_16x16x32_bf16(ah[mf], bh, acc[mf][nf], 0,0,0);
        acc[mf][nf] = __builtin_amdgcn_mfma_f32_16x16x32_bf16(ah[mf], bl, acc[mf][nf], 0,0,0);
        acc[mf][nf] = __builtin_amdgcn_mfma_f32_16x16x32_bf16(al[mf], bh, acc[mf][nf], 0,0,0);
      }
    }
    __syncthreads();
  }

  #pragma unroll
  for (int mf=0; mf<4; mf++){
    int r0 = mbase + wr*64 + mf*16 + kq*4;
    #pragma unroll
    for (int nf=0; nf<4; nf++){
      int c = nbase + wc*64 + nf*16 + l16;
      #pragma unroll
      for (int r=0;r<4;r++)
        C[(size_t)(r0+r)*ldc + c] = acc[mf][nf][r];
    }
  }
}

// ---------------------------------------------------------------------------
// x_proj MFMA kernel (in-kernel split): XD[m,0..95] = sum_k U[m,k]*W[n,k]
// ---------------------------------------------------------------------------
__global__ __launch_bounds__(256)
void xproj_mfma(const float* __restrict__ A,  // [M][2048]
                const float* __restrict__ W,  // [96][2048]
                float* __restrict__ XD)       // [M][96]
{
  __shared__ __align__(16) unsigned short Ah[32][40], Al[32][40];
  __shared__ __align__(16) unsigned short Bh[96][40], Bl[96][40];
  const int t = threadIdx.x;
  const int mbase = blockIdx.x << 5;
  const int lane = t & 63, w = t >> 6;
  const int mf = w & 1, nc0 = (w >> 1) * 48;
  const int l16 = lane & 15, kq = lane >> 4;
  const bool isA = (t < 64);
  const int srow = (isA ? t : (t - 64)) >> 1;
  const int shalf = (t & 1) << 4;
  const float* ps = isA ? (A + (size_t)(mbase + srow)*2048 + shalf)
                        : (W + (size_t)srow*2048 + shalf);
  unsigned short* dH = isA ? &Ah[srow][shalf] : &Bh[srow][shalf];
  unsigned short* dL = isA ? &Al[srow][shalf] : &Bl[srow][shalf];

  f32x4 acc[3];
  #pragma unroll
  for (int j=0;j<3;j++) acc[j] = (f32x4){0.f,0.f,0.f,0.f};

  for (int k0=0; k0<2048; k0+=32){
    CV8(dH,   dL,   ps + k0);
    CV8(dH+8, dL+8, ps + k0 + 8);
    __syncthreads();
    bf16x8 ah = *(const bf16x8*)&Ah[mf*16 + l16][kq*8];
    bf16x8 av = *(const bf16x8*)&Al[mf*16 + l16][kq*8];
    #pragma unroll
    for (int nf=0; nf<3; nf++){
      int br = nc0 + nf*16 + l16;
      bf16x8 bh = *(const bf16x8*)&Bh[br][kq*8];
      bf16x8 bl = *(const bf16x8*)&Bl[br][kq*8];
      acc[nf] = __builtin_amdgcn_mfma_f32_16x16x32_bf16(ah, bh, acc[nf], 0,0,0);
      acc[nf] = __builtin_amdgcn_mfma_f32_16x16x32_bf16(ah, bl, acc[nf], 0,0,0);
      acc[nf] = __builtin_amdgcn_mfma_f32_16x16x32_bf16(av, bh, acc[nf], 0,0,0);
    }
    __syncthreads();
  }
  #pragma unroll
  for (int nf=0; nf<3; nf++){
    int c = nc0 + nf*16 + l16;
    int r0 = mbase + mf*16 + kq*4;
    #pragma unroll
    for (int r=0;r<4;r++)
      XD[(size_t)(r0+r)*96 + c] = acc[nf][r];
  }
}

// ---------------------------------------------------------------------------
// fp32 NT GEMM (dt_proj, K=64): C = softplus(A*B^T + ebias[n]).  N mult 128.
// ---------------------------------------------------------------------------
__global__ __launch_bounds__(256)
void gemm_dt(const float* __restrict__ A, int lda,
             const float* __restrict__ B, int ldb,
             float* __restrict__ C, int ldc,
             int K, const float* __restrict__ ebias)
{
  __shared__ float As[16][132];
  __shared__ float Bs[16][132];
  int tid = threadIdx.x;
  int tx = tid & 15, ty = tid >> 4;
  int mbase = blockIdx.y << 7;
  int nbase = blockIdx.x << 7;
  float acc[8][8];
  #pragma unroll
  for (int i=0;i<8;i++)
    #pragma unroll
    for (int j=0;j<8;j++) acc[i][j]=0.f;

  for (int k0=0;k0<K;k0+=16){
    #pragma unroll
    for (int it=0; it<2; it++){
      int idx = tid + (it<<8);
      int row = idx >> 2;
      int kq  = (idx & 3) << 2;
      float4 va = *(const float4*)(A + (size_t)(mbase+row)*lda + k0 + kq);
      As[kq+0][row]=va.x; As[kq+1][row]=va.y; As[kq+2][row]=va.z; As[kq+3][row]=va.w;
      float4 vb = *(const float4*)(B + (size_t)(nbase+row)*ldb + k0 + kq);
      Bs[kq+0][row]=vb.x; Bs[kq+1][row]=vb.y; Bs[kq+2][row]=vb.z; Bs[kq+3][row]=vb.w;
    }
    __syncthreads();
    #pragma unroll
    for (int k=0;k<16;k++){
      float a[8], bb[8];
      *(float4*)&a[0]  = *(const float4*)&As[k][ty<<2];
      *(float4*)&a[4]  = *(const float4*)&As[k][64+(ty<<2)];
      *(float4*)&bb[0] = *(const float4*)&Bs[k][tx<<2];
      *(float4*)&bb[4] = *(const float4*)&Bs[k][64+(tx<<2)];
      #pragma unroll
      for (int i=0;i<8;i++)
        #pragma unroll
        for (int j=0;j<8;j++)
          acc[i][j] = fmaf(a[i], bb[j], acc[i][j]);
    }
    __syncthreads();
  }

  int n0 = nbase + (tx<<2);
  int n1 = n0 + 64;
  float4 eb0 = *(const float4*)(ebias + n0);
  float4 eb1 = *(const float4*)(ebias + n1);
  #pragma unroll
  for (int i=0;i<8;i++){
    int mrow = mbase + ((i<4) ? ((ty<<2)+i) : (64 + (ty<<2) + (i-4)));
    float4 c0 = make_float4(acc[i][0],acc[i][1],acc[i][2],acc[i][3]);
    float4 c1 = make_float4(acc[i][4],acc[i][5],acc[i][6],acc[i][7]);
    c0.x = softplusf(c0.x+eb0.x); c0.y = softplusf(c0.y+eb0.y);
    c0.z = softplusf(c0.z+eb0.z); c0.w = softplusf(c0.w+eb0.w);
    c1.x = softplusf(c1.x+eb1.x); c1.y = softplusf(c1.y+eb1.y);
    c1.z = softplusf(c1.z+eb1.z); c1.w = softplusf(c1.w+eb1.w);
    *(float4*)(C + (size_t)mrow*ldc + n0) = c0;
    *(float4*)(C + (size_t)mrow*ldc + n1) = c1;
  }
}

// ---------------------------------------------------------------------------
// Causal depthwise conv (k=4) + bias + SiLU: XI (stride 2048) -> U.
// ---------------------------------------------------------------------------
__global__ __launch_bounds__(256)
void conv_silu_kernel(const float* __restrict__ xi, const float* __restrict__ cw,
                      const float* __restrict__ cb, float* __restrict__ xc)
{
  int idx = blockIdx.x*256 + threadIdx.x;
  int d = idx & (DINNER-1);
  int g = idx >> 11;
  int t0 = (g & 511) << 2;
  int b = g >> 9;
  float4 w4 = *(const float4*)(cw + d*4);
  float bias = cb[d];
  const float* base = xi + (size_t)b*SEQL*DINNER + d;
  float v[7];
  #pragma unroll
  for (int j=0;j<7;j++){
    int t = t0-3+j;
    v[j] = (t>=0) ? base[(size_t)t*DINNER] : 0.f;
  }
  float* outp = xc + ((size_t)b*SEQL + t0)*DINNER + d;
  #pragma unroll
  for (int j=0;j<4;j++){
    float y = fmaf(v[j+3], w4.w, fmaf(v[j+2], w4.z, fmaf(v[j+1], w4.y, fmaf(v[j], w4.x, bias))));
    outp[(size_t)j*DINNER] = siluf(y);
  }
}

// ---------------------------------------------------------------------------
// Chunked selective scan.
// PASS 1: local scan from h=0; store h_final[16] -> hfin, sum(dt) -> sumdt.
// PASS 3: local scan from hfin (true chunk-initial state); y = C.h + u*D;
//         gate with z (ZB); write y*silu(z) fp32 IN-PLACE over dt (XI).
// Thread = one (b, chunk, d). grid = NB*NC*8 blocks x 256.
// ---------------------------------------------------------------------------
template<int PASS>
__global__ __launch_bounds__(256)
void scan_chunk(const float* __restrict__ u_, float* __restrict__ dty,
                const float* __restrict__ xdbl, const float* __restrict__ zb,
                const float* __restrict__ A_log, const float* __restrict__ Dp,
                float* __restrict__ hfin, float* __restrict__ sumdt)
{
  int idx = blockIdx.x*256 + threadIdx.x;
  int d = idx & (DINNER-1);
  int g = idx >> 11;
  int c = g & (NC-1);
  int b = g >> 5;

  float A2[16];
  {
    const float* al = A_log + (size_t)d*DSTATE;
    #pragma unroll
    for (int s=0;s<16;s++) A2[s] = -expf(al[s]) * 1.44269504f;
  }
  float h[16];
  if (PASS == 1){
    #pragma unroll
    for (int s=0;s<16;s++) h[s] = 0.f;
  } else {
    const float* hp = hfin + ((size_t)g*DINNER + d)*16;
    #pragma unroll
    for (int s=0;s<16;s+=4) *(float4*)&h[s] = *(const float4*)(hp + s);
  }
  float Dv = (PASS==3) ? Dp[d] : 0.f;

  size_t row0 = (size_t)b*SEQL + (size_t)c*TC;
  const float* pu  = u_  + row0*DINNER + d;
  float*       pdt = dty + row0*DINNER + d;
  const float* pz  = zb  + row0*DINNER + d;
  const float* pbc = xdbl + row0*96 + 64;

  float Bb[2][16], Cb[2][16];
#define LOAD_BC(buf, t) { const float4* p4 = (const float4*)(pbc + (size_t)(t)*96); \
    *(float4*)&Bb[buf][0]=p4[0]; *(float4*)&Bb[buf][4]=p4[1]; \
    *(float4*)&Bb[buf][8]=p4[2]; *(float4*)&Bb[buf][12]=p4[3]; \
    if (PASS==3){ \
    *(float4*)&Cb[buf][0]=p4[4]; *(float4*)&Cb[buf][4]=p4[5]; \
    *(float4*)&Cb[buf][8]=p4[6]; *(float4*)&Cb[buf][12]=p4[7]; } }

  LOAD_BC(0, 0);
  float sdt = 0.f;
  float dt_n = pdt[0];
  float u_n  = pu[0];
  float z_n  = (PASS==3) ? pz[0] : 0.f;

  for (int t=0; t<TC; t++){
    const int cur = t & 1, nxt = cur^1;
    float dtc = dt_n, uc = u_n, zc = z_n;
    if (t+1 < TC){
      dt_n = pdt[(size_t)(t+1)*DINNER];
      u_n  = pu [(size_t)(t+1)*DINNER];
      if (PASS==3) z_n = pz[(size_t)(t+1)*DINNER];
      LOAD_BC(nxt, t+1);
    }
    if (PASS==1) sdt += dtc;
    float du = dtc*uc;
    float y = 0.f;
    #pragma unroll
    for (int s=0;s<16;s++){
      float dA = exp2f(dtc*A2[s]);
      h[s] = fmaf(dA, h[s], du*Bb[cur][s]);
      if (PASS==3) y = fmaf(h[s], Cb[cur][s], y);
    }
    if (PASS==3){
      y = fmaf(uc, Dv, y);
      pdt[(size_t)t*DINNER] = y * siluf(zc);   // gated y, in-place over dt
    }
  }
#undef LOAD_BC

  if (PASS==1){
    float* hp = hfin + ((size_t)g*DINNER + d)*16;
    #pragma unroll
    for (int s=0;s<16;s+=4) *(float4*)(hp + s) = *(const float4*)&h[s];
    sumdt[(size_t)g*DINNER + d] = sdt;
  }
}

// ---------------------------------------------------------------------------
// Propagate chunk-initial states: in-place hfin[c] := H_init(c).
// ---------------------------------------------------------------------------
__global__ __launch_bounds__(256)
void scan_prop(const float* __restrict__ A_log, float* __restrict__ hfin,
               const float* __restrict__ sumdt)
{
  int idx = blockIdx.x*256 + threadIdx.x;
  int s = idx & 15;
  int d = (idx >> 4) & (DINNER-1);
  int b = idx >> 15;
  float A2 = -expf(A_log[(size_t)d*DSTATE + s]) * 1.44269504f;
  float H = 0.f;
  size_t hbase = ((size_t)b*NC*DINNER + d)*16 + s;
  size_t sbase = (size_t)b*NC*DINNER + d;
  for (int c=0;c<NC;c++){
    float P   = exp2f(A2 * sumdt[sbase + (size_t)c*DINNER]);
    float tmp = hfin[hbase + (size_t)c*DINNER*16];
    hfin[hbase + (size_t)c*DINNER*16] = H;
    H = fmaf(P, H, tmp);
  }
}

// ---------------------------------------------------------------------------
// Launcher. Fixed: INW2 pair-split weights 33.55MB. Per batch 63.96MB:
// SH 8.39 + XI 16.78 + ZB 16.78 + U 16.78 + XD 0.79 + HF 4.19 + SD 0.26.
// NB=4 -> 289.4MB total (known ws >= 305MB). XI holds xi -> dt -> gated y.
// ---------------------------------------------------------------------------
extern "C" void kernel_launch(void* const* d_in, const int* in_sizes, int n_in,
                              void* d_out, int out_size, void* d_ws, size_t ws_size,
                              hipStream_t stream)
{
  const float* x    = (const float*)d_in[0];
  const float* in_w = (const float*)d_in[1];
  const float* cw   = (const float*)d_in[2];
  const float* cb   = (const float*)d_in[3];
  const float* xpw  = (const float*)d_in[4];
  const float* dtw  = (const float*)d_in[5];
  const float* dtb  = (const float*)d_in[6];
  const float* A_log= (const float*)d_in[7];
  const float* Dp   = (const float*)d_in[8];
  const float* ow   = (const float*)d_in[9];
  const float* nw   = (const float*)d_in[10];
  const float* nb   = (const float*)d_in[11];
  float* outF = (float*)d_out;

  const size_t fixedB = 33554432ULL;     // INW2
  const size_t perB   = 63963136ULL;
  int NB = 4;
  while (NB > 1 && fixedB + (size_t)NB*perB > ws_size) NB >>= 1;
  const int Mc = NB * SEQL;
  const int nchunk = SEQB / NB;

  unsigned short* INW2 = (unsigned short*)d_ws;            // [2][4096][2048]
  float* dyn = (float*)d_ws + fixedB/4;
  unsigned short* SH = (unsigned short*)dyn;               // Mc*2048 bf16 pair
  float* XI = dyn + (size_t)Mc*1024;                       // Mc*2048 (xi->dt->gy)
  float* ZB = XI + (size_t)Mc*2048;                        // Mc*2048 (z)
  float* U  = ZB + (size_t)Mc*2048;                        // Mc*2048 (u)
  float* XD = U  + (size_t)Mc*2048;                        // Mc*96
  float* HF = XD + (size_t)Mc*96;                          // Mc*512
  float* SD = HF + (size_t)Mc*512;                         // Mc*32

  // Pre-split in_proj weights to {h|l} pairs: rows 8192, K=1024
  wsplit2<<<8192, 256, 0, stream>>>(in_w, INW2, 1024, 8);

  for (int c = 0; c < nchunk; ++c){
    const size_t rowoff = (size_t)c * Mc;
    const float* xrows = x + rowoff * DMODEL;
    float* X1 = outF + rowoff * DMODEL;     // layer-0 out / final out rows

    for (int l = 0; l < 2; ++l){
      const float* Al = A_log + (size_t)l*DINNER*DSTATE;

      // 1. LayerNorm (+ residual for layer 1) -> SH pair
      ln_split2<<<Mc, 256, 0, stream>>>(
          (l==0) ? xrows : X1, (l==0) ? nullptr : xrows,
          nw + (size_t)l*DMODEL, nb + (size_t)l*DMODEL, SH);

      // 2. in_proj fused xi|z: cols<2048 -> XI, cols>=2048 -> ZB
      mgemm_in<<<dim3(32, Mc/128), 256, 0, stream>>>(
          SH, INW2 + (size_t)l*4096*2048, XI, ZB);

      // 3. causal conv + bias + SiLU: XI -> U
      conv_silu_kernel<<<NB*4096, 256, 0, stream>>>(
          XI, cw + (size_t)l*DINNER*4, cb + (size_t)l*DINNER, U);

      // 4. x_proj -> XD
      xproj_mfma<<<Mc/32, 256, 0, stream>>>(
          U, xpw + (size_t)l*96*DINNER, XD);

      // 5. dt_proj + bias + softplus -> XI (xi dead after conv)
      gemm_dt<<<dim3(16, Mc/128), 256, 0, stream>>>(
          XD, 96, dtw + (size_t)l*DINNER*64, 64, XI, DINNER, 64,
          dtb + (size_t)l*DINNER);

      // 6. chunked scan; pass 3 gates with z, writes fp32 in-place over XI
      scan_chunk<1><<<NB*NC*8, 256, 0, stream>>>(
          U, XI, XD, ZB, Al, Dp + (size_t)l*DINNER, HF, SD);
      scan_prop<<<NB*128, 256, 0, stream>>>(Al, HF, SD);
      scan_chunk<3><<<NB*NC*8, 256, 0, stream>>>(
          U, XI, XD, ZB, Al, Dp + (size_t)l*DINNER, HF, SD);

      // 7. out_proj (in-kernel convert): XI x ow^T -> X1 rows
      mgemm_cv<<<dim3(8, Mc/128), 256, 0, stream>>>(
          XI, DINNER, ow + (size_t)l*DMODEL*DINNER, DINNER,
          X1, DMODEL, DINNER);
    }
  }
}

// Round 7
// 3901.027 us; speedup vs baseline: 2.4397x; 1.7027x over previous
//
#include <hip/hip_runtime.h>
#include <cstddef>
#include <cstdint>

// Problem constants (from reference)
#define SEQB   8
#define SEQL   2048
#define DMODEL 1024
#define DINNER 2048
#define DSTATE 16
#define NC     32            // scan chunks along t
#define TC     64            // SEQL/NC
#define TT     8             // scan LDS tile rows (t per stage)

typedef __attribute__((ext_vector_type(4))) float f32x4;
typedef __attribute__((ext_vector_type(8))) short bf16x8;
typedef unsigned int u32;
typedef const __attribute__((address_space(1))) u32* gas_ptr;
typedef __attribute__((address_space(3))) u32* las_ptr;

__device__ __forceinline__ void gld16(const void* g, void* l){
  __builtin_amdgcn_global_load_lds((gas_ptr)g, (las_ptr)l, 16, 0, 0);
}

__device__ __forceinline__ float siluf(float x){ return x / (1.f + __expf(-x)); }
__device__ __forceinline__ float softplusf(float x){ return (x > 20.f) ? x : log1pf(__expf(x)); }

// RNE fp32 -> bf16 bits
__device__ __forceinline__ unsigned short f2bf_rne(float f){
  unsigned int u = __float_as_uint(f);
  u += 0x7FFFu + ((u>>16)&1u);
  return (unsigned short)(u>>16);
}
__device__ __forceinline__ void split_bf(float f, unsigned short& h, unsigned short& l){
  unsigned short hs = f2bf_rne(f);
  float hf = __uint_as_float(((unsigned int)hs)<<16);
  h = hs;
  l = f2bf_rne(f - hf);
}

// Convert 8 consecutive fp32 at PSRC into hi/lo bf16x8 and store (generic ptr).
#define CV8(PH, PL, PSRC) { \
  const float4* _p4 = (const float4*)(PSRC); \
  float4 _a = _p4[0], _b = _p4[1]; \
  bf16x8 _H, _L; unsigned short _h,_l; \
  split_bf(_a.x,_h,_l); _H[0]=(short)_h; _L[0]=(short)_l; \
  split_bf(_a.y,_h,_l); _H[1]=(short)_h; _L[1]=(short)_l; \
  split_bf(_a.z,_h,_l); _H[2]=(short)_h; _L[2]=(short)_l; \
  split_bf(_a.w,_h,_l); _H[3]=(short)_h; _L[3]=(short)_l; \
  split_bf(_b.x,_h,_l); _H[4]=(short)_h; _L[4]=(short)_l; \
  split_bf(_b.y,_h,_l); _H[5]=(short)_h; _L[5]=(short)_l; \
  split_bf(_b.z,_h,_l); _H[6]=(short)_h; _L[6]=(short)_l; \
  split_bf(_b.w,_h,_l); _H[7]=(short)_h; _L[7]=(short)_l; \
  *(bf16x8*)(PH) = _H; *(bf16x8*)(PL) = _L; }

// ---------------------------------------------------------------------------
// Weight pre-split PAIR {h|l}: src [R][K] fp32 -> dst [R][2K] bf16.
// ---------------------------------------------------------------------------
__global__ __launch_bounds__(256)
void wsplit2(const float* __restrict__ src, unsigned short* __restrict__ dst,
             int K, int k4shift)
{
  int idx = blockIdx.x*256 + threadIdx.x;
  int r  = idx >> k4shift;
  int c4 = idx & ((1<<k4shift)-1);
  float4 v = ((const float4*)src)[idx];
  unsigned short h,l; short4 h4, l4;
  split_bf(v.x,h,l); h4.x=(short)h; l4.x=(short)l;
  split_bf(v.y,h,l); h4.y=(short)h; l4.y=(short)l;
  split_bf(v.z,h,l); h4.z=(short)h; l4.z=(short)l;
  split_bf(v.w,h,l); h4.w=(short)h; l4.w=(short)l;
  size_t ro = (size_t)r*2*K;
  *(short4*)&dst[ro + (c4<<2)]     = h4;
  *(short4*)&dst[ro + K + (c4<<2)] = l4;
}

// ---------------------------------------------------------------------------
// LayerNorm (+ optional residual) fused with PAIR split {h|l}:
// writes Hs [row][2048] bf16 (cols 0..1023 = h, 1024..2047 = l).
// ---------------------------------------------------------------------------
__global__ __launch_bounds__(256)
void ln_split2(const float* __restrict__ a, const float* __restrict__ res,
               const float* __restrict__ w, const float* __restrict__ bias,
               unsigned short* __restrict__ Hs)
{
  int row = blockIdx.x;
  size_t off = (size_t)row * DMODEL;
  float4 v = ((const float4*)(a + off))[threadIdx.x];
  if (res){
    float4 u = ((const float4*)(res + off))[threadIdx.x];
    v.x += u.x; v.y += u.y; v.z += u.z; v.w += u.w;
  }
  float s  = v.x + v.y + v.z + v.w;
  float s2 = fmaf(v.x,v.x, fmaf(v.y,v.y, fmaf(v.z,v.z, v.w*v.w)));
  #pragma unroll
  for (int o=32;o>0;o>>=1){ s += __shfl_down(s,o,64); s2 += __shfl_down(s2,o,64); }
  __shared__ float red[8];
  int lane = threadIdx.x & 63, wid = threadIdx.x >> 6;
  if (lane==0){ red[wid]=s; red[4+wid]=s2; }
  __syncthreads();
  s  = red[0]+red[1]+red[2]+red[3];
  s2 = red[4]+red[5]+red[6]+red[7];
  float mu  = s * (1.f/DMODEL);
  float var = s2 * (1.f/DMODEL) - mu*mu;
  float rstd = rsqrtf(var + 1e-5f);
  float4 wv = ((const float4*)w)[threadIdx.x];
  float4 bv = ((const float4*)bias)[threadIdx.x];
  float4 o4;
  o4.x = (v.x-mu)*rstd*wv.x + bv.x;
  o4.y = (v.y-mu)*rstd*wv.y + bv.y;
  o4.z = (v.z-mu)*rstd*wv.z + bv.z;
  o4.w = (v.w-mu)*rstd*wv.w + bv.w;
  unsigned short h,l; short4 h4, l4;
  split_bf(o4.x,h,l); h4.x=(short)h; l4.x=(short)l;
  split_bf(o4.y,h,l); h4.y=(short)h; l4.y=(short)l;
  split_bf(o4.z,h,l); h4.z=(short)h; l4.z=(short)l;
  split_bf(o4.w,h,l); h4.w=(short)h; l4.w=(short)l;
  size_t ro = (size_t)row*2048;
  int c = threadIdx.x<<2;
  *(short4*)&Hs[ro + c]        = h4;
  *(short4*)&Hs[ro + 1024 + c] = l4;
}

// ---------------------------------------------------------------------------
// in_proj GEMM, pair-remap split-fp32: C = A*B^T with A,B stored as {h|l}
// pairs (K=1024 each half). Virtual K-loop of 3x1024 realizes hh+hl+lh.
// 128x128 tile, BK=32, gld16 staging, both-sides XOR swizzle.
// Epilogue splits cols: n<2048 -> XI (xi), else -> ZB (z). M,N mult of 128.
// ---------------------------------------------------------------------------
__global__ __launch_bounds__(256)
void mgemm_in(const unsigned short* __restrict__ A,   // [M][2048] {h|l}
              const unsigned short* __restrict__ B,   // [4096][2048] {h|l}
              float* __restrict__ XI, float* __restrict__ ZB)
{
  __shared__ __align__(16) unsigned short As[128*32];
  __shared__ __align__(16) unsigned short Bs[128*32];
  const int t = threadIdx.x;
  const int mbase = blockIdx.y << 7, nbase = blockIdx.x << 7;
  const int lane = t & 63, w = t >> 6;
  const int wr = w >> 1, wc = w & 1;
  const int l16 = lane & 15, kq = lane >> 4;

  const int srow = t >> 2, sl = t & 3;
  const int co0 = ((sl ^ ((srow>>1)&3)) << 3);
  const int co1 = ((sl ^ (((srow+64)>>1)&3)) << 3);
  const unsigned short* pa0 = A + (size_t)(mbase+srow)*2048 + co0;
  const unsigned short* pa1 = A + (size_t)(mbase+srow+64)*2048 + co1;
  const unsigned short* pb0 = B + (size_t)(nbase+srow)*2048 + co0;
  const unsigned short* pb1 = B + (size_t)(nbase+srow+64)*2048 + co1;
  unsigned short* da0 = &As[srow*32 + sl*8];
  unsigned short* da1 = &As[(srow+64)*32 + sl*8];
  unsigned short* db0 = &Bs[srow*32 + sl*8];
  unsigned short* db1 = &Bs[(srow+64)*32 + sl*8];

  f32x4 acc[4][4];
  #pragma unroll
  for (int i=0;i<4;i++)
    #pragma unroll
    for (int j=0;j<4;j++) acc[i][j] = (f32x4){0.f,0.f,0.f,0.f};

  #pragma unroll
  for (int kb=0; kb<3; kb++){
    const int ao = (kb==2) ? 1024 : 0;   // A: {h,h,l}
    const int bo = (kb==1) ? 1024 : 0;   // B: {h,l,h}
    for (int kk=0; kk<1024; kk+=32){
      gld16(pa0 + ao + kk, da0);
      gld16(pa1 + ao + kk, da1);
      gld16(pb0 + bo + kk, db0);
      gld16(pb1 + bo + kk, db1);
      __syncthreads();
      bf16x8 af[4];
      #pragma unroll
      for (int mf=0; mf<4; mf++){
        int ra = wr*64 + mf*16 + l16;
        af[mf] = *(const bf16x8*)&As[ra*32 + ((kq ^ ((ra>>1)&3))<<3)];
      }
      #pragma unroll
      for (int nf=0; nf<4; nf++){
        int rb = wc*64 + nf*16 + l16;
        bf16x8 bfr = *(const bf16x8*)&Bs[rb*32 + ((kq ^ ((rb>>1)&3))<<3)];
        #pragma unroll
        for (int mf=0; mf<4; mf++)
          acc[mf][nf] = __builtin_amdgcn_mfma_f32_16x16x32_bf16(af[mf], bfr, acc[mf][nf], 0,0,0);
      }
      __syncthreads();
    }
  }

  float* Cd = (nbase < 2048) ? XI : ZB;
  const int cb = (nbase < 2048) ? nbase : (nbase - 2048);
  #pragma unroll
  for (int mf=0; mf<4; mf++){
    int r0 = mbase + wr*64 + mf*16 + kq*4;
    #pragma unroll
    for (int nf=0; nf<4; nf++){
      int c = cb + wc*64 + nf*16 + l16;
      #pragma unroll
      for (int r=0;r<4;r++)
        Cd[(size_t)(r0+r)*2048 + c] = acc[mf][nf][r];
    }
  }
}

// ---------------------------------------------------------------------------
// out_proj GEMM (round-4 proven): fp32 in/out, in-kernel split, 3 MFMAs/frag.
// ---------------------------------------------------------------------------
__global__ __launch_bounds__(256)
void mgemm_cv(const float* __restrict__ A, int lda,
              const float* __restrict__ B, int ldb,
              float* __restrict__ C, int ldc, int K)
{
  __shared__ __align__(16) unsigned short Ah[128][40], Al[128][40];
  __shared__ __align__(16) unsigned short Bh[128][40], Bl[128][40];
  const int t = threadIdx.x;
  const int mbase = blockIdx.y << 7, nbase = blockIdx.x << 7;
  const int srow = t >> 1, shalf = (t & 1) << 4;
  const float* pa = A + (size_t)(mbase + srow)*lda + shalf;
  const float* pb = B + (size_t)(nbase + srow)*ldb + shalf;

  const int lane = t & 63, w = t >> 6;
  const int wr = w >> 1, wc = w & 1;
  const int l16 = lane & 15, kq = lane >> 4;

  f32x4 acc[4][4];
  #pragma unroll
  for (int i=0;i<4;i++)
    #pragma unroll
    for (int j=0;j<4;j++) acc[i][j] = (f32x4){0.f,0.f,0.f,0.f};

  for (int k0 = 0; k0 < K; k0 += 32){
    CV8(&Ah[srow][shalf],   &Al[srow][shalf],   pa + k0);
    CV8(&Ah[srow][shalf+8], &Al[srow][shalf+8], pa + k0 + 8);
    CV8(&Bh[srow][shalf],   &Bl[srow][shalf],   pb + k0);
    CV8(&Bh[srow][shalf+8], &Bl[srow][shalf+8], pb + k0 + 8);
    __syncthreads();
    bf16x8 ah[4], al[4];
    #pragma unroll
    for (int mf=0; mf<4; mf++){
      int ar = wr*64 + mf*16 + l16;
      ah[mf] = *(const bf16x8*)&Ah[ar][kq*8];
      al[mf] = *(const bf16x8*)&Al[ar][kq*8];
    }
    #pragma unroll
    for (int nf=0; nf<4; nf++){
      int br = wc*64 + nf*16 + l16;
      bf16x8 bh = *(const bf16x8*)&Bh[br][kq*8];
      bf16x8 bl = *(const bf16x8*)&Bl[br][kq*8];
      #pragma unroll
      for (int mf=0; mf<4; mf++){
        acc[mf][nf] = __builtin_amdgcn_mfma_f32_16x16x32_bf16(ah[mf], bh, acc[mf][nf], 0,0,0);
        acc[mf][nf] = __builtin_amdgcn_mfma_f32_16x16x32_bf16(ah[mf], bl, acc[mf][nf], 0,0,0);
        acc[mf][nf] = __builtin_amdgcn_mfma_f32_16x16x32_bf16(al[mf], bh, acc[mf][nf], 0,0,0);
      }
    }
    __syncthreads();
  }

  #pragma unroll
  for (int mf=0; mf<4; mf++){
    int r0 = mbase + wr*64 + mf*16 + kq*4;
    #pragma unroll
    for (int nf=0; nf<4; nf++){
      int c = nbase + wc*64 + nf*16 + l16;
      #pragma unroll
      for (int r=0;r<4;r++)
        C[(size_t)(r0+r)*ldc + c] = acc[mf][nf][r];
    }
  }
}

// ---------------------------------------------------------------------------
// x_proj MFMA kernel (in-kernel split): XD[m,0..95] = sum_k U[m,k]*W[n,k]
// ---------------------------------------------------------------------------
__global__ __launch_bounds__(256)
void xproj_mfma(const float* __restrict__ A,  // [M][2048]
                const float* __restrict__ W,  // [96][2048]
                float* __restrict__ XD)       // [M][96]
{
  __shared__ __align__(16) unsigned short Ah[32][40], Al[32][40];
  __shared__ __align__(16) unsigned short Bh[96][40], Bl[96][40];
  const int t = threadIdx.x;
  const int mbase = blockIdx.x << 5;
  const int lane = t & 63, w = t >> 6;
  const int mf = w & 1, nc0 = (w >> 1) * 48;
  const int l16 = lane & 15, kq = lane >> 4;
  const bool isA = (t < 64);
  const int srow = (isA ? t : (t - 64)) >> 1;
  const int shalf = (t & 1) << 4;
  const float* ps = isA ? (A + (size_t)(mbase + srow)*2048 + shalf)
                        : (W + (size_t)srow*2048 + shalf);
  unsigned short* dH = isA ? &Ah[srow][shalf] : &Bh[srow][shalf];
  unsigned short* dL = isA ? &Al[srow][shalf] : &Bl[srow][shalf];

  f32x4 acc[3];
  #pragma unroll
  for (int j=0;j<3;j++) acc[j] = (f32x4){0.f,0.f,0.f,0.f};

  for (int k0=0; k0<2048; k0+=32){
    CV8(dH,   dL,   ps + k0);
    CV8(dH+8, dL+8, ps + k0 + 8);
    __syncthreads();
    bf16x8 ah = *(const bf16x8*)&Ah[mf*16 + l16][kq*8];
    bf16x8 av = *(const bf16x8*)&Al[mf*16 + l16][kq*8];
    #pragma unroll
    for (int nf=0; nf<3; nf++){
      int br = nc0 + nf*16 + l16;
      bf16x8 bh = *(const bf16x8*)&Bh[br][kq*8];
      bf16x8 bl = *(const bf16x8*)&Bl[br][kq*8];
      acc[nf] = __builtin_amdgcn_mfma_f32_16x16x32_bf16(ah, bh, acc[nf], 0,0,0);
      acc[nf] = __builtin_amdgcn_mfma_f32_16x16x32_bf16(ah, bl, acc[nf], 0,0,0);
      acc[nf] = __builtin_amdgcn_mfma_f32_16x16x32_bf16(av, bh, acc[nf], 0,0,0);
    }
    __syncthreads();
  }
  #pragma unroll
  for (int nf=0; nf<3; nf++){
    int c = nc0 + nf*16 + l16;
    int r0 = mbase + mf*16 + kq*4;
    #pragma unroll
    for (int r=0;r<4;r++)
      XD[(size_t)(r0+r)*96 + c] = acc[nf][r];
  }
}

// ---------------------------------------------------------------------------
// fp32 NT GEMM (dt_proj, K=64): C = softplus(A*B^T + ebias[n]).  N mult 128.
// ---------------------------------------------------------------------------
__global__ __launch_bounds__(256)
void gemm_dt(const float* __restrict__ A, int lda,
             const float* __restrict__ B, int ldb,
             float* __restrict__ C, int ldc,
             int K, const float* __restrict__ ebias)
{
  __shared__ float As[16][132];
  __shared__ float Bs[16][132];
  int tid = threadIdx.x;
  int tx = tid & 15, ty = tid >> 4;
  int mbase = blockIdx.y << 7;
  int nbase = blockIdx.x << 7;
  float acc[8][8];
  #pragma unroll
  for (int i=0;i<8;i++)
    #pragma unroll
    for (int j=0;j<8;j++) acc[i][j]=0.f;

  for (int k0=0;k0<K;k0+=16){
    #pragma unroll
    for (int it=0; it<2; it++){
      int idx = tid + (it<<8);
      int row = idx >> 2;
      int kq  = (idx & 3) << 2;
      float4 va = *(const float4*)(A + (size_t)(mbase+row)*lda + k0 + kq);
      As[kq+0][row]=va.x; As[kq+1][row]=va.y; As[kq+2][row]=va.z; As[kq+3][row]=va.w;
      float4 vb = *(const float4*)(B + (size_t)(nbase+row)*ldb + k0 + kq);
      Bs[kq+0][row]=vb.x; Bs[kq+1][row]=vb.y; Bs[kq+2][row]=vb.z; Bs[kq+3][row]=vb.w;
    }
    __syncthreads();
    #pragma unroll
    for (int k=0;k<16;k++){
      float a[8], bb[8];
      *(float4*)&a[0]  = *(const float4*)&As[k][ty<<2];
      *(float4*)&a[4]  = *(const float4*)&As[k][64+(ty<<2)];
      *(float4*)&bb[0] = *(const float4*)&Bs[k][tx<<2];
      *(float4*)&bb[4] = *(const float4*)&Bs[k][64+(tx<<2)];
      #pragma unroll
      for (int i=0;i<8;i++)
        #pragma unroll
        for (int j=0;j<8;j++)
          acc[i][j] = fmaf(a[i], bb[j], acc[i][j]);
    }
    __syncthreads();
  }

  int n0 = nbase + (tx<<2);
  int n1 = n0 + 64;
  float4 eb0 = *(const float4*)(ebias + n0);
  float4 eb1 = *(const float4*)(ebias + n1);
  #pragma unroll
  for (int i=0;i<8;i++){
    int mrow = mbase + ((i<4) ? ((ty<<2)+i) : (64 + (ty<<2) + (i-4)));
    float4 c0 = make_float4(acc[i][0],acc[i][1],acc[i][2],acc[i][3]);
    float4 c1 = make_float4(acc[i][4],acc[i][5],acc[i][6],acc[i][7]);
    c0.x = softplusf(c0.x+eb0.x); c0.y = softplusf(c0.y+eb0.y);
    c0.z = softplusf(c0.z+eb0.z); c0.w = softplusf(c0.w+eb0.w);
    c1.x = softplusf(c1.x+eb1.x); c1.y = softplusf(c1.y+eb1.y);
    c1.z = softplusf(c1.z+eb1.z); c1.w = softplusf(c1.w+eb1.w);
    *(float4*)(C + (size_t)mrow*ldc + n0) = c0;
    *(float4*)(C + (size_t)mrow*ldc + n1) = c1;
  }
}

// ---------------------------------------------------------------------------
// Causal depthwise conv (k=4) + bias + SiLU: XI (stride 2048) -> U.
// ---------------------------------------------------------------------------
__global__ __launch_bounds__(256)
void conv_silu_kernel(const float* __restrict__ xi, const float* __restrict__ cw,
                      const float* __restrict__ cb, float* __restrict__ xc)
{
  int idx = blockIdx.x*256 + threadIdx.x;
  int d = idx & (DINNER-1);
  int g = idx >> 11;
  int t0 = (g & 511) << 2;
  int b = g >> 9;
  float4 w4 = *(const float4*)(cw + d*4);
  float bias = cb[d];
  const float* base = xi + (size_t)b*SEQL*DINNER + d;
  float v[7];
  #pragma unroll
  for (int j=0;j<7;j++){
    int t = t0-3+j;
    v[j] = (t>=0) ? base[(size_t)t*DINNER] : 0.f;
  }
  float* outp = xc + ((size_t)b*SEQL + t0)*DINNER + d;
  #pragma unroll
  for (int j=0;j<4;j++){
    float y = fmaf(v[j+3], w4.w, fmaf(v[j+2], w4.z, fmaf(v[j+1], w4.y, fmaf(v[j], w4.x, bias))));
    outp[(size_t)j*DINNER] = siluf(y);
  }
}

// ---------------------------------------------------------------------------
// Chunked selective scan, LDS-tiled + fully-unrolled (static B/C indexing).
// Block = 256 threads = one (g = b*NC + c, 256-wide d-slice).
// Tiles of TT=8 t-rows staged via global_load_lds (1KB/wave bursts);
// per-step reads are LDS scalars (2-way bank alias = free).
// PASS 1: local scan from h=0; write h_final -> hfin, sum(dt) -> sumdt.
// PASS 3: local scan from hfin; y=(C.h+u*D)*silu(z) into LDS tile, then
//         cooperative float4 writeback in-place over dt (dty).
// B/C ping-pong prefetch in REGISTERS (compile-time cur/nxt via unroll).
// ---------------------------------------------------------------------------
template<int PASS>
__global__ __launch_bounds__(256)
void scan_chunk(const float* __restrict__ u_, float* __restrict__ dty,
                const float* __restrict__ xdbl, const float* __restrict__ zb,
                const float* __restrict__ A_log, const float* __restrict__ Dp,
                float* __restrict__ hfin, float* __restrict__ sumdt)
{
  __shared__ __align__(16) float Tdt[TT][256];
  __shared__ __align__(16) float Tu [TT][256];
  __shared__ __align__(16) float Tz [TT][256];

  const int tid = threadIdx.x;
  const int idx = blockIdx.x*256 + tid;
  const int d = idx & (DINNER-1);
  const int g = idx >> 11;          // uniform per block
  const int cck = g & (NC-1);
  const int bb = g >> 5;
  const int wv = tid >> 6, ln = tid & 63;
  const int dbase = (blockIdx.x << 8) & (DINNER-1);

  float A2[16];
  {
    const float* al = A_log + (size_t)d*DSTATE;
    #pragma unroll
    for (int s=0;s<16;s++) A2[s] = -expf(al[s]) * 1.44269504f;
  }
  float h[16];
  if (PASS == 1){
    #pragma unroll
    for (int s=0;s<16;s++) h[s] = 0.f;
  } else {
    const float* hp = hfin + ((size_t)g*DINNER + d)*16;
    #pragma unroll
    for (int s=0;s<16;s+=4) *(float4*)&h[s] = *(const float4*)(hp + s);
  }
  const float Dv = (PASS==3) ? Dp[d] : 0.f;

  const size_t row0 = (size_t)bb*SEQL + (size_t)cck*TC;
  const float* pbc = xdbl + row0*96 + 64;

  float Bb[2][16], Cb[2][16];
#define LOAD_BC(buf, t) { const float4* p4 = (const float4*)(pbc + (size_t)(t)*96); \
    *(float4*)&Bb[buf][0]=p4[0]; *(float4*)&Bb[buf][4]=p4[1]; \
    *(float4*)&Bb[buf][8]=p4[2]; *(float4*)&Bb[buf][12]=p4[3]; \
    if (PASS==3){ \
    *(float4*)&Cb[buf][0]=p4[4]; *(float4*)&Cb[buf][4]=p4[5]; \
    *(float4*)&Cb[buf][8]=p4[6]; *(float4*)&Cb[buf][12]=p4[7]; } }

  LOAD_BC(0, 0);
  float sdt = 0.f;

  for (int t0 = 0; t0 < TC; t0 += TT){
    // ---- stage TT rows of dt/u/(z): per wave 2 rows, 1KB contiguous each
    #pragma unroll
    for (int q=0;q<2;q++){
      int r = q*4 + wv;
      size_t go = (row0 + t0 + r)*DINNER + dbase + ln*4;
      gld16(dty + go, &Tdt[r][0]);
      gld16(u_  + go, &Tu[r][0]);
      if (PASS==3) gld16(zb + go, &Tz[r][0]);
    }
    __syncthreads();

    #pragma unroll
    for (int tt=0; tt<TT; tt++){
      const int t = t0 + tt;
      const int cur = tt & 1, nxt = cur^1;   // compile-time (t0 even)
      float dtc = Tdt[tt][tid];
      float uc  = Tu[tt][tid];
      float zc  = (PASS==3) ? Tz[tt][tid] : 0.f;
      if (t+1 < TC) LOAD_BC(nxt, t+1);
      if (PASS==1) sdt += dtc;
      float du = dtc*uc;
      float y = 0.f;
      #pragma unroll
      for (int s=0;s<16;s++){
        float dA = exp2f(dtc*A2[s]);
        h[s] = fmaf(dA, h[s], du*Bb[cur][s]);
        if (PASS==3) y = fmaf(h[s], Cb[cur][s], y);
      }
      if (PASS==3){
        y = fmaf(uc, Dv, y);
        Tdt[tt][tid] = y * siluf(zc);       // own slot, no race
      }
    }

    if (PASS==3){
      __syncthreads();
      #pragma unroll
      for (int q=0;q<2;q++){
        int r = q*4 + wv;
        float4 v = *(const float4*)&Tdt[r][ln*4];
        *(float4*)(dty + (row0 + t0 + r)*DINNER + dbase + ln*4) = v;
      }
    }
    __syncthreads();
  }
#undef LOAD_BC

  if (PASS==1){
    float* hp = hfin + ((size_t)g*DINNER + d)*16;
    #pragma unroll
    for (int s=0;s<16;s+=4) *(float4*)(hp + s) = *(const float4*)&h[s];
    sumdt[(size_t)g*DINNER + d] = sdt;
  }
}

// ---------------------------------------------------------------------------
// Propagate chunk-initial states: in-place hfin[c] := H_init(c).
// ---------------------------------------------------------------------------
__global__ __launch_bounds__(256)
void scan_prop(const float* __restrict__ A_log, float* __restrict__ hfin,
               const float* __restrict__ sumdt)
{
  int idx = blockIdx.x*256 + threadIdx.x;
  int s = idx & 15;
  int d = (idx >> 4) & (DINNER-1);
  int b = idx >> 15;
  float A2 = -expf(A_log[(size_t)d*DSTATE + s]) * 1.44269504f;
  float H = 0.f;
  size_t hbase = ((size_t)b*NC*DINNER + d)*16 + s;
  size_t sbase = (size_t)b*NC*DINNER + d;
  for (int c=0;c<NC;c++){
    float P   = exp2f(A2 * sumdt[sbase + (size_t)c*DINNER]);
    float tmp = hfin[hbase + (size_t)c*DINNER*16];
    hfin[hbase + (size_t)c*DINNER*16] = H;
    H = fmaf(P, H, tmp);
  }
}

// ---------------------------------------------------------------------------
// Launcher. Fixed: INW2 pair-split weights 33.55MB. Per batch 63.96MB.
// NB=4 -> 289.4MB total (known ws >= 305MB). XI holds xi -> dt -> gated y.
// ---------------------------------------------------------------------------
extern "C" void kernel_launch(void* const* d_in, const int* in_sizes, int n_in,
                              void* d_out, int out_size, void* d_ws, size_t ws_size,
                              hipStream_t stream)
{
  const float* x    = (const float*)d_in[0];
  const float* in_w = (const float*)d_in[1];
  const float* cw   = (const float*)d_in[2];
  const float* cb   = (const float*)d_in[3];
  const float* xpw  = (const float*)d_in[4];
  const float* dtw  = (const float*)d_in[5];
  const float* dtb  = (const float*)d_in[6];
  const float* A_log= (const float*)d_in[7];
  const float* Dp   = (const float*)d_in[8];
  const float* ow   = (const float*)d_in[9];
  const float* nw   = (const float*)d_in[10];
  const float* nb   = (const float*)d_in[11];
  float* outF = (float*)d_out;

  const size_t fixedB = 33554432ULL;     // INW2
  const size_t perB   = 63963136ULL;
  int NB = 4;
  while (NB > 1 && fixedB + (size_t)NB*perB > ws_size) NB >>= 1;
  const int Mc = NB * SEQL;
  const int nchunk = SEQB / NB;

  unsigned short* INW2 = (unsigned short*)d_ws;            // [2][4096][2048]
  float* dyn = (float*)d_ws + fixedB/4;
  unsigned short* SH = (unsigned short*)dyn;               // Mc*2048 bf16 pair
  float* XI = dyn + (size_t)Mc*1024;                       // Mc*2048 (xi->dt->gy)
  float* ZB = XI + (size_t)Mc*2048;                        // Mc*2048 (z)
  float* U  = ZB + (size_t)Mc*2048;                        // Mc*2048 (u)
  float* XD = U  + (size_t)Mc*2048;                        // Mc*96
  float* HF = XD + (size_t)Mc*96;                          // Mc*512
  float* SD = HF + (size_t)Mc*512;                         // Mc*32

  // Pre-split in_proj weights to {h|l} pairs: rows 8192, K=1024
  wsplit2<<<8192, 256, 0, stream>>>(in_w, INW2, 1024, 8);

  for (int c = 0; c < nchunk; ++c){
    const size_t rowoff = (size_t)c * Mc;
    const float* xrows = x + rowoff * DMODEL;
    float* X1 = outF + rowoff * DMODEL;     // layer-0 out / final out rows

    for (int l = 0; l < 2; ++l){
      const float* Al = A_log + (size_t)l*DINNER*DSTATE;

      // 1. LayerNorm (+ residual for layer 1) -> SH pair
      ln_split2<<<Mc, 256, 0, stream>>>(
          (l==0) ? xrows : X1, (l==0) ? nullptr : xrows,
          nw + (size_t)l*DMODEL, nb + (size_t)l*DMODEL, SH);

      // 2. in_proj fused xi|z: cols<2048 -> XI, cols>=2048 -> ZB
      mgemm_in<<<dim3(32, Mc/128), 256, 0, stream>>>(
          SH, INW2 + (size_t)l*4096*2048, XI, ZB);

      // 3. causal conv + bias + SiLU: XI -> U
      conv_silu_kernel<<<NB*4096, 256, 0, stream>>>(
          XI, cw + (size_t)l*DINNER*4, cb + (size_t)l*DINNER, U);

      // 4. x_proj -> XD
      xproj_mfma<<<Mc/32, 256, 0, stream>>>(
          U, xpw + (size_t)l*96*DINNER, XD);

      // 5. dt_proj + bias + softplus -> XI (xi dead after conv)
      gemm_dt<<<dim3(16, Mc/128), 256, 0, stream>>>(
          XD, 96, dtw + (size_t)l*DINNER*64, 64, XI, DINNER, 64,
          dtb + (size_t)l*DINNER);

      // 6. chunked scan; pass 3 gates with z, writes fp32 in-place over XI
      scan_chunk<1><<<NB*NC*8, 256, 0, stream>>>(
          U, XI, XD, ZB, Al, Dp + (size_t)l*DINNER, HF, SD);
      scan_prop<<<NB*128, 256, 0, stream>>>(Al, HF, SD);
      scan_chunk<3><<<NB*NC*8, 256, 0, stream>>>(
          U, XI, XD, ZB, Al, Dp + (size_t)l*DINNER, HF, SD);

      // 7. out_proj (in-kernel convert): XI x ow^T -> X1 rows
      mgemm_cv<<<dim3(8, Mc/128), 256, 0, stream>>>(
          XI, DINNER, ow + (size_t)l*DMODEL*DINNER, DINNER,
          X1, DMODEL, DINNER);
    }
  }
}